// Round 5
// baseline (284.914 us; speedup 1.0000x reference)
//
#include <hip/hip_runtime.h>

typedef __bf16 bf16_t;
typedef __bf16 bf16x4 __attribute__((ext_vector_type(4)));
typedef __bf16 bf16x8 __attribute__((ext_vector_type(8)));
typedef float f32x4 __attribute__((ext_vector_type(4)));

#define MFMA16(a, b, c) __builtin_amdgcn_mfma_f32_16x16x32_bf16((a), (b), (c), 0, 0, 0)

// ---------------------------------------------------------------------------
// Swizzled 64-col bf16 tile helpers (stage + frag-read sides use same swizzle).
// ---------------------------------------------------------------------------
__device__ __forceinline__ const bf16_t* tile_ptr(const bf16_t* t, int row, int kchunk) {
    return t + row * 64 + (((kchunk ^ (row & 7))) << 3);
}

__device__ __forceinline__ void stage64(const bf16_t* __restrict__ gbase, size_t gstride,
                                        bf16_t* lds_rowbase, int lane) {
    const int rr = lane >> 3, cl = lane & 7;
    const bf16_t* g = gbase + (size_t)rr * gstride + ((cl ^ rr) << 3);
    __builtin_amdgcn_global_load_lds((__attribute__((address_space(1))) const void*)g,
                                     (__attribute__((address_space(3))) void*)lds_rowbase,
                                     16, 0, 0);
}

// Swizzled 128x128 bf16 C-tile address (epilogue transpose buffer).
__device__ __forceinline__ int cs_addr(int m, int n) {
    return m * 128 + ((((n >> 3) ^ ((m >> 3) & 7))) << 3) + (n & 7);
}

// ---------------------------------------------------------------------------
// Kernel 0: fp32 -> bf16 conversion pre-pass.
// ---------------------------------------------------------------------------
__global__ void __launch_bounds__(256) k_cvt(
    const float* __restrict__ q, const float* __restrict__ wi, const float* __restrict__ wo,
    bf16_t* __restrict__ qb, bf16_t* __restrict__ wib, bf16_t* __restrict__ wob)
{
    const int g = blockIdx.x * 256 + threadIdx.x;
    const float* src; bf16_t* dst; int off;
    if (g < 1048576)      { src = q;  dst = qb;  off = g; }
    else if (g < 1441792) { src = wi; dst = wib; off = g - 1048576; }
    else                  { src = wo; dst = wob; off = g - 1441792; }
    const float4* s4 = (const float4*)(src + (size_t)off * 8);
    float4 a = s4[0], b = s4[1];
    bf16x8 v;
    v[0] = (bf16_t)a.x; v[1] = (bf16_t)a.y; v[2] = (bf16_t)a.z; v[3] = (bf16_t)a.w;
    v[4] = (bf16_t)b.x; v[5] = (bf16_t)b.y; v[6] = (bf16_t)b.z; v[7] = (bf16_t)b.w;
    *(bf16x8*)(dst + (size_t)off * 8) = v;
}

// ---------------------------------------------------------------------------
// Kernel 1: QKV projection (de-interleaved n' space, LDS-transposed epilogue).
//   Qh/Kh: [head][si][d]  (Q scaled by (1/8)*log2(e) -- exp2 fold)
//   Vt:    [head][si>>3][d][si&7]
// ---------------------------------------------------------------------------
__global__ void __launch_bounds__(256) k_qkv(
    const bf16_t* __restrict__ A, const bf16_t* __restrict__ W,
    const float* __restrict__ bias,
    bf16_t* __restrict__ Qh, bf16_t* __restrict__ Kh, bf16_t* __restrict__ Vt)
{
    __shared__ bf16_t smem[16384];          // As|Bs during K-loop; Cs in epilogue
    bf16_t* As = smem;
    bf16_t* Bs = smem + 8192;
    const int m0 = blockIdx.x * 128;
    const int n0 = blockIdx.y * 128;        // permuted n' space
    const int which = n0 >> 10;             // 0=Q, 1=K, 2=V (block-uniform)
    const int hbase = (n0 & 1023) >> 6;
    const int t = threadIdx.x;
    const int wave = t >> 6, lane = t & 63;
    const int quad = lane >> 4, l16 = lane & 15;
    const int wm = (wave & 1) * 64, wn = (wave >> 1) * 64;

    f32x4 acc[4][4] = {};

    for (int k0 = 0; k0 < 1024; k0 += 64) {
        __syncthreads();
        #pragma unroll
        for (int p = 0; p < 4; ++p) {
            const int rb = wave * 32 + p * 8;
            stage64(A + (size_t)(m0 + rb) * 1024 + k0, 1024, As + rb * 64, lane);
            const int np = n0 + rb;
            const int wrow = ((np & 1023) >> 6) * 192 + which * 64 + (np & 63);
            stage64(W + (size_t)wrow * 1024 + k0, 1024, Bs + rb * 64, lane);
        }
        __syncthreads();
        #pragma unroll
        for (int ks = 0; ks < 2; ++ks) {
            bf16x8 af[4], bf[4];
            #pragma unroll
            for (int i = 0; i < 4; ++i)
                af[i] = *(const bf16x8*)tile_ptr(As, wm + i * 16 + l16, ks * 4 + quad);
            #pragma unroll
            for (int j = 0; j < 4; ++j)
                bf[j] = *(const bf16x8*)tile_ptr(Bs, wn + j * 16 + l16, ks * 4 + quad);
            #pragma unroll
            for (int i = 0; i < 4; ++i)
                #pragma unroll
                for (int j = 0; j < 4; ++j)
                    acc[i][j] = MFMA16(af[i], bf[j], acc[i][j]);
        }
    }

    // ---- Epilogue phase 1: C tile (bias+scale applied) -> swizzled LDS ----
    __syncthreads();
    const float scale = (which == 0) ? 0.180336880111112f : 1.0f;  // 1/8 * log2(e)
    #pragma unroll
    for (int j = 0; j < 4; ++j) {
        const int nl = wn + j * 16 + l16;
        const float bv = bias[(hbase + (nl >> 6)) * 192 + which * 64 + (nl & 63)];
        #pragma unroll
        for (int i = 0; i < 4; ++i) {
            #pragma unroll
            for (int rg = 0; rg < 4; ++rg) {
                const int ml = wm + i * 16 + quad * 4 + rg;
                smem[cs_addr(ml, nl)] = (bf16_t)((acc[i][j][rg] + bv) * scale);
            }
        }
    }
    __syncthreads();

    // ---- Epilogue phase 2: coalesced stores ----
    const int si0 = m0 >> 3;
    if (which < 2) {
        bf16_t* dst = which ? Kh : Qh;
        #pragma unroll
        for (int u = 0; u < 4; ++u) {
            const int unit = wave * 4 + u;          // (h, bi)
            const int h = unit >> 3, bi = unit & 7;
            const int head = bi * 16 + hbase + h;
            #pragma unroll
            for (int pass = 0; pass < 2; ++pass) {
                const int si = pass * 8 + (lane >> 3);
                const int dc = lane & 7;
                const int ml = si * 8 + bi;
                const int nch = (h * 8 + dc) ^ (si & 7);
                bf16x8 v = *(const bf16x8*)&smem[ml * 128 + nch * 8];
                *(bf16x8*)(dst + (size_t)head * 65536 + (size_t)(si0 + si) * 64 + dc * 8) = v;
            }
        }
    } else {
        #pragma unroll
        for (int u = 0; u < 8; ++u) {
            const int unit = wave * 8 + u;          // (h, bi, c)
            const int h = unit >> 4, bi = (unit >> 1) & 7, c = unit & 1;
            const int head = bi * 16 + hbase + h;
            const int d = lane;
            bf16x8 v;
            #pragma unroll
            for (int e = 0; e < 8; ++e) {
                const int ml = (c * 8 + e) * 8 + bi;
                const int nch = (h * 8 + (d >> 3)) ^ e;
                v[e] = smem[ml * 128 + nch * 8 + (d & 7)];
            }
            *(bf16x8*)(Vt + (size_t)head * 65536 +
                       (size_t)(si0 / 8 + c) * 512 + (size_t)d * 8) = v;
        }
    }
}

// ---------------------------------------------------------------------------
// Kernel 2: fused attention. Block = (head, 256-row q-tile); each wave owns
// 64 q-rows (4 halves of 16) so K/V frag reads amortize over 4x the MFMAs.
// S^T via MFMA(K,Q): lanes hold 4 consecutive keys -> b64 P-writes. Q frags
// straight from global; ones-column synthesized in regs; XCD-affine swizzle.
// ---------------------------------------------------------------------------
__global__ void __launch_bounds__(256, 2) k_attn(
    const bf16_t* __restrict__ Qh, const bf16_t* __restrict__ Kh,
    const bf16_t* __restrict__ Vg, bf16_t* __restrict__ Ctx)
{
    __shared__ bf16_t Ks[64 * 64];
    __shared__ bf16_t Vts[64 * 64];     // V^T tile (rows=d, cols=key), XOR-swizzled
    __shared__ bf16_t Pw[4][64 * 64];   // per-wave P [qrow 0..63][key], XOR-swizzled

    const int bid = blockIdx.x;
    const int head = (bid & 7) * 16 + ((bid >> 3) & 15);  // bid%8 = XCD (heuristic)
    const int qt = bid >> 7;                              // 0..3 (256-row q tile)
    const int t = threadIdx.x;
    const int wave = t >> 6, lane = t & 63;
    const int quad = lane >> 4, l16 = lane & 15;

    const bf16_t* Qg = Qh + (size_t)head * 65536 + (size_t)qt * 16384;
    const bf16_t* Kg = Kh + (size_t)head * 65536;
    const bf16_t* Vgh = Vg + (size_t)head * 65536;   // [sc][d][s7]

    // Q b-frags from global: lane l16 = q-row, 16B contiguous per lane
    bf16x8 qf[4][2];
    #pragma unroll
    for (int half = 0; half < 4; ++half)
        #pragma unroll
        for (int ks = 0; ks < 2; ++ks)
            qf[half][ks] = *(const bf16x8*)(
                Qg + (size_t)(wave * 64 + half * 16 + l16) * 64 + ks * 32 + quad * 8);

    // ones-column B-frag: column 0 of the ones block -> l16==0 lanes
    bf16x8 ones;
    #pragma unroll
    for (int e = 0; e < 8; ++e) ones[e] = (bf16_t)((l16 == 0) ? 1.0f : 0.0f);

    f32x4 vacc[4][5] = {};   // [q-half][ctx d-tiles 0..3, rowsum 4]

    for (int kt = 0; kt < 16; ++kt) {
        __syncthreads();
        #pragma unroll
        for (int p = 0; p < 2; ++p) {
            const int rb = wave * 16 + p * 8;
            stage64(Kg + (size_t)(kt * 64 + rb) * 64, 64, Ks + rb * 64, lane);
            {   // V^T staging from [sc][d][s7]
                const int rr = lane >> 3, cl = lane & 7;
                const bf16_t* g = Vgh + (size_t)(kt * 8 + (cl ^ rr)) * 512
                                      + (size_t)(rb + rr) * 8;
                __builtin_amdgcn_global_load_lds(
                    (__attribute__((address_space(1))) const void*)g,
                    (__attribute__((address_space(3))) void*)(Vts + rb * 64), 16, 0, 0);
            }
        }
        __syncthreads();

        // K A-frags: shared across all 4 q-halves
        bf16x8 kf[2][4];
        #pragma unroll
        for (int ks = 0; ks < 2; ++ks)
            #pragma unroll
            for (int j = 0; j < 4; ++j)
                kf[ks][j] = *(const bf16x8*)tile_ptr(Ks, j * 16 + l16, ks * 4 + quad);

        // Per half: S^T = K Q^T, then P = exp2(S^T) -> Pw (b64 writes)
        #pragma unroll
        for (int half = 0; half < 4; ++half) {
            f32x4 s[4] = {};
            #pragma unroll
            for (int j = 0; j < 4; ++j) {
                s[j] = MFMA16(kf[0][j], qf[half][0], s[j]);
                s[j] = MFMA16(kf[1][j], qf[half][1], s[j]);
            }
            const int row = half * 16 + l16;
            #pragma unroll
            for (int j = 0; j < 4; ++j) {
                bf16x4 pv;
                #pragma unroll
                for (int rg = 0; rg < 4; ++rg)
                    pv[rg] = (bf16_t)exp2f(s[j][rg]);
                const int chunk = j * 2 + (quad >> 1);
                *(bf16x4*)&Pw[wave][row * 64 + ((chunk ^ (row & 7)) << 3) + (quad & 1) * 4] = pv;
            }
        }
        asm volatile("s_waitcnt lgkmcnt(0)" ::: "memory");  // wave-local write->read

        // ctx_aug += P @ [V | 1] ; V frags shared across the 4 halves
        #pragma unroll
        for (int ks = 0; ks < 2; ++ks) {
            bf16x8 vf[4];
            #pragma unroll
            for (int n = 0; n < 4; ++n)
                vf[n] = *(const bf16x8*)tile_ptr(Vts, n * 16 + l16, ks * 4 + quad);
            #pragma unroll
            for (int half = 0; half < 4; ++half) {
                bf16x8 pf = *(const bf16x8*)tile_ptr(Pw[wave], half * 16 + l16, ks * 4 + quad);
                #pragma unroll
                for (int n = 0; n < 4; ++n)
                    vacc[half][n] = MFMA16(pf, vf[n], vacc[half][n]);
                vacc[half][4] = MFMA16(pf, ones, vacc[half][4]);
            }
        }
    }

    const int bi = head >> 4, h = head & 15;
    #pragma unroll
    for (int half = 0; half < 4; ++half) {
        #pragma unroll
        for (int rg = 0; rg < 4; ++rg) {
            const float l = __shfl(vacc[half][4][rg], lane & 48, 64);
            const float inv = 1.0f / l;
            const int si = qt * 256 + wave * 64 + half * 16 + quad * 4 + rg;
            #pragma unroll
            for (int n = 0; n < 4; ++n)
                Ctx[((size_t)si * 8 + bi) * 1024 + h * 64 + n * 16 + l16] =
                    (bf16_t)(vacc[half][n][rg] * inv);
        }
    }
}

// ---------------------------------------------------------------------------
// Kernel 3: output projection (m97 structure).
// ---------------------------------------------------------------------------
__global__ void __launch_bounds__(256) k_out(
    const bf16_t* __restrict__ A, const bf16_t* __restrict__ W,
    const float* __restrict__ bias, float* __restrict__ out)
{
    __shared__ bf16_t As[128 * 64];
    __shared__ bf16_t Bs[128 * 64];
    const int m0 = blockIdx.x * 128;
    const int n0 = blockIdx.y * 128;
    const int t = threadIdx.x;
    const int wave = t >> 6, lane = t & 63;
    const int quad = lane >> 4, l16 = lane & 15;
    const int wm = (wave & 1) * 64, wn = (wave >> 1) * 64;

    f32x4 acc[4][4] = {};

    for (int k0 = 0; k0 < 1024; k0 += 64) {
        __syncthreads();
        #pragma unroll
        for (int p = 0; p < 4; ++p) {
            const int rb = wave * 32 + p * 8;
            stage64(A + (size_t)(m0 + rb) * 1024 + k0, 1024, As + rb * 64, lane);
            stage64(W + (size_t)(n0 + rb) * 1024 + k0, 1024, Bs + rb * 64, lane);
        }
        __syncthreads();
        #pragma unroll
        for (int ks = 0; ks < 2; ++ks) {
            bf16x8 af[4], bf[4];
            #pragma unroll
            for (int i = 0; i < 4; ++i)
                af[i] = *(const bf16x8*)tile_ptr(As, wm + i * 16 + l16, ks * 4 + quad);
            #pragma unroll
            for (int j = 0; j < 4; ++j)
                bf[j] = *(const bf16x8*)tile_ptr(Bs, wn + j * 16 + l16, ks * 4 + quad);
            #pragma unroll
            for (int i = 0; i < 4; ++i)
                #pragma unroll
                for (int j = 0; j < 4; ++j)
                    acc[i][j] = MFMA16(af[i], bf[j], acc[i][j]);
        }
    }

    #pragma unroll
    for (int j = 0; j < 4; ++j) {
        const int n = n0 + wn + j * 16 + l16;
        const float bv = bias[n];
        #pragma unroll
        for (int i = 0; i < 4; ++i) {
            #pragma unroll
            for (int rg = 0; rg < 4; ++rg) {
                const int m = m0 + wm + i * 16 + quad * 4 + rg;
                out[(size_t)m * 1024 + n] = acc[i][j][rg] + bv;
            }
        }
    }
}

// ---------------------------------------------------------------------------
extern "C" void kernel_launch(void* const* d_in, const int* in_sizes, int n_in,
                              void* d_out, int out_size, void* d_ws, size_t ws_size,
                              hipStream_t stream)
{
    const float* query = (const float*)d_in[0];
    const float* in_w  = (const float*)d_in[3];
    const float* in_b  = (const float*)d_in[4];
    const float* out_w = (const float*)d_in[5];
    const float* out_b = (const float*)d_in[6];
    float* out = (float*)d_out;

    bf16_t* Wi  = (bf16_t*)d_ws;                 //  3,145,728
    bf16_t* Wo  = Wi + (size_t)3145728;          //  1,048,576
    bf16_t* Qh  = Wo + (size_t)1048576;          //  8,388,608
    bf16_t* Kh  = Qh + (size_t)8388608;          //  8,388,608
    bf16_t* Vt  = Kh + (size_t)8388608;          //  8,388,608
    bf16_t* Aq  = Vt + (size_t)8388608;          //  8,388,608 (Ctx after k_qkv)
    bf16_t* Ctx = Aq;

    k_cvt<<<dim3(6144), 256, 0, stream>>>(query, in_w, out_w, Aq, Wi, Wo);
    k_qkv<<<dim3(64, 24), 256, 0, stream>>>(Aq, Wi, in_b, Qh, Kh, Vt);
    k_attn<<<dim3(512), 256, 0, stream>>>(Qh, Kh, Vt, Ctx);
    k_out<<<dim3(64, 8), 256, 0, stream>>>(Ctx, Wo, out_b, out);
}